// Round 16
// baseline (183.963 us; speedup 1.0000x reference)
//
#include <hip/hip_runtime.h>

// Fused transformer block: x -> MHA(causal) -> +res -> FFN -> +res
// B=2 T=4096 D=512 H=8 HS=64.
// GEMMs: 128xBN BK=64 (+XCD swizzle). qkv epilogue pre-scales Q by 0.125/ln2
// and writes V directly transposed into vt. Attention: 512 blocks x 2 chained
// items, KVBLK=128 super-steps (2x 64-key halves per barrier; 9 super-steps
// per item-pair, perfectly balanced). Merge: 1024 blocks.

typedef __attribute__((ext_vector_type(8))) short bf16x8;
typedef __attribute__((ext_vector_type(4))) float f32x4;
typedef __attribute__((ext_vector_type(16))) float f32x16;
typedef unsigned short u16;

__device__ __forceinline__ u16 f2bf(float f) {
  union { float f; unsigned int i; } u; u.f = f;
  unsigned int r = u.i + 0x7fffu + ((u.i >> 16) & 1u);
  return (u16)(r >> 16);
}
__device__ __forceinline__ float bf2f(u16 s) {
  union { unsigned int i; float f; } u; u.i = ((unsigned int)s) << 16;
  return u.f;
}
__device__ __forceinline__ void gload16(const void* g, void* l) {
  __builtin_amdgcn_global_load_lds((const __attribute__((address_space(1))) void*)g,
                                   (__attribute__((address_space(3))) void*)l,
                                   16, 0, 0);
}

// permlane32_swap: a' = (lane<32)? a_own : b_partner ; b' = (lane<32)? a_partner : b_own
__device__ __forceinline__ void plswap_u(unsigned &a, unsigned &b) {
#if defined(__has_builtin) && __has_builtin(__builtin_amdgcn_permlane32_swap)
  auto r = __builtin_amdgcn_permlane32_swap(a, b, false, false);
  a = (unsigned)r[0]; b = (unsigned)r[1];
#else
  asm("v_permlane32_swap_b32 %0, %1" : "+v"(a), "+v"(b));
#endif
}
__device__ __forceinline__ void plswap_f(float &a, float &b) {
  unsigned ua = __builtin_bit_cast(unsigned, a), ub = __builtin_bit_cast(unsigned, b);
  plswap_u(ua, ub);
  a = __builtin_bit_cast(float, ua); b = __builtin_bit_cast(float, ub);
}

__device__ __forceinline__ float tsum16(const f32x16 v) {
  float a = v[0] + v[8],  b = v[1] + v[9];
  float c = v[2] + v[10], d = v[3] + v[11];
  float e = v[4] + v[12], f = v[5] + v[13];
  float g = v[6] + v[14], h = v[7] + v[15];
  a += e; b += f; c += g; d += h;
  a += c; b += d;
  return a + b;
}

// ---------- fused prep: x cast (fp32->bf16) + all weight transposes ----------
__global__ __launch_bounds__(256) void prep_kernel(
    const float* __restrict__ x, const float* __restrict__ Wq,
    const float* __restrict__ Wk, const float* __restrict__ Wv,
    const float* __restrict__ Wproj, const float* __restrict__ W1,
    const float* __restrict__ W2, ushort4* __restrict__ xb4,
    u16* __restrict__ wqkv_t, u16* __restrict__ wproj_t,
    u16* __restrict__ w1_t, u16* __restrict__ w2_t) {
  const int i = blockIdx.x;
  if (i >= 3072) {
    int idx = (i - 3072) * 256 + threadIdx.x;
    float4 v = ((const float4*)x)[idx];
    ushort4 o; o.x = f2bf(v.x); o.y = f2bf(v.y); o.z = f2bf(v.z); o.w = f2bf(v.w);
    xb4[idx] = o;
    return;
  }
  const float* in; u16* out; int C, ldo, bx, by;
  if (i < 768) {
    int which = i >> 8, r = i & 255;
    const float* W = which == 0 ? Wq : (which == 1 ? Wk : Wv);
    int bz = r >> 5;
    in = W + bz * 32768;
    out = wqkv_t + which * 262144 + bz * 32768;
    C = 64; ldo = 512; bx = r & 1; by = (r >> 1) & 15;
  } else if (i < 1024) {
    int r = i - 768;
    in = Wproj; out = wproj_t; C = 512; ldo = 512; bx = r & 15; by = r >> 4;
  } else if (i < 2048) {
    int r = i - 1024;
    in = W1; out = w1_t; C = 2048; ldo = 512; bx = r & 63; by = r >> 6;
  } else {
    int r = i - 2048;
    in = W2; out = w2_t; C = 512; ldo = 2048; bx = r & 15; by = r >> 4;
  }
  __shared__ float t[32][33];
  int c0 = bx * 32, r0 = by * 32;
  int tx = threadIdx.x & 31, ty = threadIdx.x >> 5;
#pragma unroll
  for (int k = 0; k < 4; k++)
    t[ty + 8 * k][tx] = in[(long)(r0 + ty + 8 * k) * C + c0 + tx];
  __syncthreads();
#pragma unroll
  for (int k = 0; k < 4; k++)
    out[(long)(c0 + ty + 8 * k) * ldo + r0 + tx] = f2bf(t[tx][ty + 8 * k]);
}

// ---------- GEMM: C[M,N] = A[M,K] @ Bt[N,K]^T, 128xBN tile, BK=64 ----------
// MODE 0: bf16. MODE 1: bf16 = acc+bias+bf2f(resb). MODE 2: bf16 = relu(acc+bias).
// MODE 3: f32 = acc+bias+bf2f(resb).
// MODE 4: qkv — Q cols (<512) scaled by 0.125/ln2; K cols plain;
//         V cols (>=1024) written TRANSPOSED into vtOut[bh][e][t] (ushort4).
template <int MODE, int BN>
__global__ __launch_bounds__(256) void gemm_bt_kernel(
    const u16* __restrict__ A, const u16* __restrict__ Bt, void* __restrict__ Out,
    const float* __restrict__ bias, const u16* __restrict__ resb,
    u16* __restrict__ vtOut, int N, int K) {
  __shared__ __align__(16) char As[128 * 128];
  __shared__ __align__(16) char Bs[BN * 128];
  const int tid = threadIdx.x;
  const int lane = tid & 63, w = tid >> 6;
  const int l15 = lane & 15, l4 = lane >> 4;
  const int nx = gridDim.x, nwg = nx * gridDim.y;
  int id = blockIdx.y * nx + blockIdx.x;
  id = (id & 7) * (nwg >> 3) + (id >> 3);  // XCD-bijective (nwg % 8 == 0)
  const long m0 = (long)(id / nx) * 128;
  const long n0 = (long)(id % nx) * BN;
  const int wm = (w >> 1) * 64, wn = (w & 1) * (BN / 2);
  const int NB = BN / 32;

  f32x4 acc[4][NB] = {};

  for (int kt = 0; kt < K; kt += 64) {
#pragma unroll
    for (int i = 0; i < 4; i++) {
      int basechunk = i * 256 + w * 64;
      int chunk = basechunk + lane;
      int row = chunk >> 3, c = chunk & 7;
      int sc = c ^ (row & 7);
      gload16(A + (m0 + row) * K + kt + sc * 8, As + basechunk * 16);
    }
#pragma unroll
    for (int i = 0; i < BN / 32; i++) {
      int basechunk = i * 256 + w * 64;
      int chunk = basechunk + lane;
      int row = chunk >> 3, c = chunk & 7;
      int sc = c ^ (row & 7);
      gload16(Bt + (n0 + row) * K + kt + sc * 8, Bs + basechunk * 16);
    }
    __syncthreads();
#pragma unroll
    for (int kk = 0; kk < 2; kk++) {
      bf16x8 a[4], b[NB];
#pragma unroll
      for (int m = 0; m < 4; m++) {
        int row = wm + m * 16 + l15;
        int ch = (kk * 4 + l4) ^ (row & 7);
        a[m] = *(const bf16x8*)(As + row * 128 + ch * 16);
      }
#pragma unroll
      for (int n = 0; n < NB; n++) {
        int row = wn + n * 16 + l15;
        int ch = (kk * 4 + l4) ^ (row & 7);
        b[n] = *(const bf16x8*)(Bs + row * 128 + ch * 16);
      }
#pragma unroll
      for (int m = 0; m < 4; m++)
#pragma unroll
        for (int n = 0; n < NB; n++)
          acc[m][n] = __builtin_amdgcn_mfma_f32_16x16x32_bf16(a[m], b[n], acc[m][n], 0, 0, 0);
    }
    __syncthreads();
  }

#pragma unroll
  for (int m = 0; m < 4; m++) {
#pragma unroll
    for (int n = 0; n < NB; n++) {
      long gcol = n0 + wn + n * 16 + l15;
      if (MODE == 4) {
        long grow0 = m0 + wm + m * 16 + l4 * 4;
        if (gcol < 1024) {
          const float s = (gcol < 512) ? 0.18033688f : 1.0f;
#pragma unroll
          for (int r = 0; r < 4; r++)
            ((u16*)Out)[(grow0 + r) * N + gcol] = f2bf(acc[m][n][r] * s);
        } else {
          int bb = (int)(grow0 >> 12);
          long trow0 = grow0 & 4095;
          int hc = (int)(gcol - 1024);
          int bhh = bb * 8 + (hc >> 6), e = hc & 63;
          ushort4 o;
          o.x = f2bf(acc[m][n][0]);
          o.y = f2bf(acc[m][n][1]);
          o.z = f2bf(acc[m][n][2]);
          o.w = f2bf(acc[m][n][3]);
          *(ushort4*)(vtOut + (long)bhh * 262144 + (long)e * 4096 + trow0) = o;
        }
      } else {
#pragma unroll
        for (int r = 0; r < 4; r++) {
          long grow = m0 + wm + m * 16 + l4 * 4 + r;
          float v = acc[m][n][r];
          if (MODE == 0) {
            ((u16*)Out)[grow * N + gcol] = f2bf(v);
          } else if (MODE == 1) {
            v += bias[gcol] + bf2f(resb[grow * N + gcol]);
            ((u16*)Out)[grow * N + gcol] = f2bf(v);
          } else if (MODE == 2) {
            v += bias[gcol];
            v = v > 0.f ? v : 0.f;
            ((u16*)Out)[grow * N + gcol] = f2bf(v);
          } else {
            v += bias[gcol] + bf2f(resb[grow * N + gcol]);
            ((float*)Out)[grow * N + gcol] = v;
          }
        }
      }
    }
  }
}

// ---------- flash attention (causal), 256-row Q tiles, quarter-KV split ----------
// Q pre-scaled -> p = exp2(s) directly. 512 blocks, 2 chained items (g, 1023-g).
// KVBLK=128 super-steps: two 64-key halves per barrier. Per item-pair:
// ceil((qt+1)/2)+ceil((16-qt)/2) = 9 super-steps for every block.
__global__ __launch_bounds__(512, 4) void attn_kernel(
    const u16* __restrict__ qkv, const u16* __restrict__ vt,
    u16* __restrict__ pacc, float* __restrict__ pli) {
  __shared__ __align__(16) char Ks[2][128 * 128];  // [buf][key128][e64] bf16
  __shared__ __align__(16) char Vs[2][64 * 256];   // [buf][e64][key128] bf16
  const int tid = threadIdx.x;
  const int lane = tid & 63, w = tid >> 6;   // w in 0..7
  const int l31 = lane & 31, l5 = lane >> 5;

  const int g = blockIdx.x;

  for (int it = 0; it < 2; ++it) {
    const int item = it ? 1023 - g : g;
    const int qt = item >> 6;          // 0..15
    const int bh = (item >> 2) & 15;
    const int qq = item & 3;           // KV quarter
    const int b = bh >> 3, h = bh & 7;
    const int qt0 = qt * 256;
    const int L = qt + 1;              // 64-key tiles in this quarter
    const int j0 = qq * L, j1 = j0 + L;
    const int jdiag = 4 * qt;
    const int SS = (L + 1) >> 1;       // 128-key super-steps
    const u16* qbase = qkv + (long)b * 4096 * 1536 + h * 64;
    const u16* kbase = qbase + 512;
    const u16* vtbase = vt + (long)bh * 64 * 4096;

    // Q direct to registers (B-operand layout): aq[kk] = Q[q=qrow][e=16kk+8*l5+j]
    const int qrow_g = qt0 + w * 32 + l31;
    bf16x8 aq[4];
    {
      const u16* qp = qbase + (long)qrow_g * 1536 + l5 * 8;
#pragma unroll
      for (int kk = 0; kk < 4; kk++) aq[kk] = *(const bf16x8*)(qp + kk * 16);
    }

    // staging pointers. K: 128 rows x 128B = 1024 chunks, 2 per thread
    //   (i=0,1): row_i = i*64 + tid>>3, c = tid&7, sc = c^(row&7) (row&7 same for both i)
    // V: 64 rows x 256B = 1024 chunks, 2 per thread:
    //   row_i = i*32 + tid>>4, c = tid&15, hf = c>>3, scl = (c&7)^(row&7)
    const int krow = tid >> 3;
    const int ksc = (tid & 7) ^ (krow & 7);
    const u16* kp = kbase + (long)(j0 * 64 + krow) * 1536 + ksc * 8;
    const int vrow = tid >> 4, vc = tid & 15;
    const int vhf = vc >> 3, vscl = (vc & 7) ^ (vrow & 7);
    const u16* vp = vtbase + (long)vrow * 4096 + j0 * 64 + vhf * 64 + vscl * 8;
    gload16(kp, Ks[0] + w * 1024);
    gload16(kp + 64 * 1536, Ks[0] + 8192 + w * 1024);
    gload16(vp, Vs[0] + w * 1024);
    gload16(vp + 32 * 4096, Vs[0] + 8192 + w * 1024);
    __syncthreads();

    f32x16 oacc[2] = {};
    float li = 0.f;

    for (int ss = 0; ss < SS; ++ss) {
      const int cur = ss & 1;
      if (ss + 1 < SS) {
        kp += 128 * 1536;
        vp += 128;
        gload16(kp, Ks[cur ^ 1] + w * 1024);
        gload16(kp + 64 * 1536, Ks[cur ^ 1] + 8192 + w * 1024);
        gload16(vp, Vs[cur ^ 1] + w * 1024);
        gload16(vp + 32 * 4096, Vs[cur ^ 1] + 8192 + w * 1024);
      }

#pragma unroll
      for (int kh = 0; kh < 2; ++kh) {
        const int j = j0 + 2 * ss + kh;
        if (j >= j1) break;  // odd-L tail: second half beyond quarter
        const bool diag = (j >= jdiag);
        const int thr = qrow_g - j * 64;  // key_local <= thr is valid

        // two independent 32-key halves; st lives briefly -> arch VGPRs
#pragma unroll
        for (int n = 0; n < 2; n++) {
          // S^T[key][q] = K @ Q^T : key = kh*64 + n*32 + 4*l5 + (reg&3) + 8*(reg>>2)... (n,reg map)
          f32x16 st = {};
          __builtin_amdgcn_s_setprio(1);
#pragma unroll
          for (int kk = 0; kk < 4; kk++) {
            int ch = ((l5 + 2 * kk) ^ (l31 & 7)) * 16;
            bf16x8 ak = *(const bf16x8*)(Ks[cur] + (kh * 64 + n * 32 + l31) * 128 + ch);
            st = __builtin_amdgcn_mfma_f32_32x32x16_bf16(ak, aq[kk], st, 0, 0, 0);
          }
          __builtin_amdgcn_s_setprio(0);

          if (diag) {
#pragma unroll
            for (int reg = 0; reg < 16; reg++) {
              int key = n * 32 + 4 * l5 + (reg & 3) + 8 * (reg >> 2);
              if (key > thr) st[reg] = -1e30f;
            }
          }

          // scale-free exp: p = exp2(s); masked -> 0
#pragma unroll
          for (int reg = 0; reg < 16; reg++)
            st[reg] = exp2f(st[reg]);
          li += tsum16(st);

          // pack to bf16, exchange halves, and immediately PV this 32-key half
#pragma unroll
          for (int jj = 0; jj < 2; jj++) {
            unsigned w0, w1, w2, w3;
            {
              unsigned pa, pb;
              asm("v_cvt_pk_bf16_f32 %0, %1, %2" : "=v"(pa) : "v"(st[(2 * jj) * 4 + 0]), "v"(st[(2 * jj) * 4 + 1]));
              asm("v_cvt_pk_bf16_f32 %0, %1, %2" : "=v"(pb) : "v"(st[(2 * jj + 1) * 4 + 0]), "v"(st[(2 * jj + 1) * 4 + 1]));
              plswap_u(pa, pb);
              w0 = pa; w2 = pb;
            }
            {
              unsigned pa, pb;
              asm("v_cvt_pk_bf16_f32 %0, %1, %2" : "=v"(pa) : "v"(st[(2 * jj) * 4 + 2]), "v"(st[(2 * jj) * 4 + 3]));
              asm("v_cvt_pk_bf16_f32 %0, %1, %2" : "=v"(pb) : "v"(st[(2 * jj + 1) * 4 + 2]), "v"(st[(2 * jj + 1) * 4 + 3]));
              plswap_u(pa, pb);
              w1 = pa; w3 = pb;
            }
            union { unsigned u[4]; bf16x8 v; } bp;
            bp.u[0] = w0; bp.u[1] = w1; bp.u[2] = w2; bp.u[3] = w3;
            int s2 = 2 * n + jj;
            int ch = ((l5 + 2 * s2) ^ (l31 & 7)) * 16;
            bf16x8 av0 = *(const bf16x8*)(Vs[cur] + l31 * 256 + kh * 128 + ch);
            bf16x8 av1 = *(const bf16x8*)(Vs[cur] + (32 + l31) * 256 + kh * 128 + ch);
            __builtin_amdgcn_s_setprio(1);
            oacc[0] = __builtin_amdgcn_mfma_f32_32x32x16_bf16(av0, bp.v, oacc[0], 0, 0, 0);
            oacc[1] = __builtin_amdgcn_mfma_f32_32x32x16_bf16(av1, bp.v, oacc[1], 0, 0, 0);
            __builtin_amdgcn_s_setprio(0);
          }
        }
      }
      __syncthreads();  // drains prefetch; fences Ks/Vs buffer reuse
    }

    // cross-half li reduce (once per item)
    {
      float ta = li, tb = li;
      plswap_f(ta, tb);
      li = ta + tb;
    }

    // write partial: pacc bf16 [item][256 q][64 e] (unnormalized), pli[item][256 q]
    u16* pa = pacc + (long)item * 16384;
#pragma unroll
    for (int ne = 0; ne < 2; ne++)
#pragma unroll
      for (int gg = 0; gg < 4; gg++) {
        ushort4 o;
        o.x = f2bf(oacc[ne][4 * gg + 0]);
        o.y = f2bf(oacc[ne][4 * gg + 1]);
        o.z = f2bf(oacc[ne][4 * gg + 2]);
        o.w = f2bf(oacc[ne][4 * gg + 3]);
        *(ushort4*)(pa + (w * 32 + l31) * 64 + ne * 32 + 4 * l5 + 8 * gg) = o;
      }
    if (l5 == 0) pli[(long)item * 256 + w * 32 + l31] = li;
  }
}

// ---------- merge the four KV quarters: O = sum(acc_q) / sum(li_q) ----------
// 1024 blocks (4/CU): block = tile*4 + rowgroup; each handles 64 of 256 rows.
__global__ __launch_bounds__(256) void attn_merge_kernel(
    const u16* __restrict__ pacc, const float* __restrict__ pli, u16* __restrict__ attnb) {
  int tile = blockIdx.x >> 2;      // qt*16 + bh
  int rg = blockIdx.x & 3;         // row group (64 rows)
  int qt = tile >> 4, bh = tile & 15;
  int b = bh >> 3, h = bh & 7;
  int ibase = qt * 64 + bh * 4;
  const u16* pq[4];
  const float* lq[4];
#pragma unroll
  for (int q = 0; q < 4; q++) {
    pq[q] = pacc + (long)(ibase + q) * 16384;
    lq[q] = pli + (long)(ibase + q) * 256;
  }
  int t = threadIdx.x;
  int cg = (t & 15) * 4;
  int rsub = t >> 4;
#pragma unroll
  for (int pass = 0; pass < 4; ++pass) {
    int row = rg * 64 + pass * 16 + rsub;
    float denom = lq[0][row] + lq[1][row] + lq[2][row] + lq[3][row];
    float acc0 = 0.f, acc1 = 0.f, acc2 = 0.f, acc3 = 0.f;
#pragma unroll
    for (int q = 0; q < 4; q++) {
      ushort4 u = *(const ushort4*)(pq[q] + row * 64 + cg);
      acc0 += bf2f(u.x);
      acc1 += bf2f(u.y);
      acc2 += bf2f(u.z);
      acc3 += bf2f(u.w);
    }
    float inv = 1.f / denom;
    ushort4 o;
    o.x = f2bf(acc0 * inv);
    o.y = f2bf(acc1 * inv);
    o.z = f2bf(acc2 * inv);
    o.w = f2bf(acc3 * inv);
    *(ushort4*)(attnb + ((long)(b * 4096 + qt * 256 + row)) * 512 + h * 64 + cg) = o;
  }
}

extern "C" void kernel_launch(void* const* d_in, const int* in_sizes, int n_in,
                              void* d_out, int out_size, void* d_ws, size_t ws_size,
                              hipStream_t stream) {
  const float* x = (const float*)d_in[0];
  const float* Wq = (const float*)d_in[1];
  const float* Wk = (const float*)d_in[2];
  const float* Wv = (const float*)d_in[3];
  const float* Wproj = (const float*)d_in[4];
  const float* bproj = (const float*)d_in[5];
  const float* W1 = (const float*)d_in[6];
  const float* b1 = (const float*)d_in[7];
  const float* W2 = (const float*)d_in[8];
  const float* b2 = (const float*)d_in[9];

  char* ws = (char*)d_ws;
  u16* xb      = (u16*)(ws);             // [8192][512]   bf16 x
  u16* wqkv_t  = (u16*)(ws + 8388608);   // [1536][512]
  u16* wproj_t = (u16*)(ws + 9961472);   // [512][512]
  u16* w1_t    = (u16*)(ws + 10485760);  // [2048][512]
  u16* w2_t    = (u16*)(ws + 12582912);  // [512][2048]
  u16* qkv     = (u16*)(ws + 14680064);  // [8192][1536]  (q pre-scaled; V cols unused)
  u16* vt      = (u16*)(ws + 39845888);  // [16][64][4096]
  u16* attnb   = (u16*)(ws + 48234496);  // [8192][512]
  u16* x1b     = (u16*)(ws + 56623104);  // [8192][512]   x + sa_out
  u16* hbuf    = (u16*)(ws + 65011712);  // [8192][2048]  relu(ffn1)
  // attention partials alias later-written buffers (safe by stream order):
  float* pli   = (float*)(ws + 56623104 + 2097152);  // 1MB inside x1b region
  u16* pacc    = (u16*)(ws + 65011712);              // 32MB inside hbuf region

  prep_kernel<<<7168, 256, 0, stream>>>(x, Wq, Wk, Wv, Wproj, W1, W2,
                                        (ushort4*)xb, wqkv_t, wproj_t, w1_t, w2_t);

  gemm_bt_kernel<4, 128><<<dim3(12, 64), 256, 0, stream>>>(xb, wqkv_t, qkv, nullptr, nullptr, vt, 1536, 512);
  attn_kernel<<<512, 512, 0, stream>>>(qkv, vt, pacc, pli);
  attn_merge_kernel<<<1024, 256, 0, stream>>>(pacc, pli, attnb);
  gemm_bt_kernel<1, 64><<<dim3(8, 64), 256, 0, stream>>>(attnb, wproj_t, x1b, bproj, xb, nullptr, 512, 512);
  gemm_bt_kernel<2, 128><<<dim3(16, 64), 256, 0, stream>>>(x1b, w1_t, hbuf, b1, nullptr, nullptr, 2048, 512);
  gemm_bt_kernel<3, 64><<<dim3(8, 64), 256, 0, stream>>>(hbuf, w2_t, d_out, b2, x1b, nullptr, 512, 2048);
}

// Round 17
// 178.999 us; speedup vs baseline: 1.0277x; 1.0277x over previous
//
#include <hip/hip_runtime.h>

// Fused transformer block: x -> MHA(causal) -> +res -> FFN -> +res
// B=2 T=4096 D=512 H=8 HS=64.
// GEMMs: 128xBN BK=64 (+XCD swizzle). qkv epilogue pre-scales Q by 0.125/ln2
// and writes V directly transposed into vt (no transpose_v kernel).
// Attention: 512 blocks x 2 chained items (17 steps each, perfectly balanced).
// Merge: 1024 blocks (4/CU). proj residual from bf16 xb.

typedef __attribute__((ext_vector_type(8))) short bf16x8;
typedef __attribute__((ext_vector_type(4))) float f32x4;
typedef __attribute__((ext_vector_type(16))) float f32x16;
typedef unsigned short u16;

__device__ __forceinline__ u16 f2bf(float f) {
  union { float f; unsigned int i; } u; u.f = f;
  unsigned int r = u.i + 0x7fffu + ((u.i >> 16) & 1u);
  return (u16)(r >> 16);
}
__device__ __forceinline__ float bf2f(u16 s) {
  union { unsigned int i; float f; } u; u.i = ((unsigned int)s) << 16;
  return u.f;
}
__device__ __forceinline__ void gload16(const void* g, void* l) {
  __builtin_amdgcn_global_load_lds((const __attribute__((address_space(1))) void*)g,
                                   (__attribute__((address_space(3))) void*)l,
                                   16, 0, 0);
}

// permlane32_swap: a' = (lane<32)? a_own : b_partner ; b' = (lane<32)? a_partner : b_own
__device__ __forceinline__ void plswap_u(unsigned &a, unsigned &b) {
#if defined(__has_builtin) && __has_builtin(__builtin_amdgcn_permlane32_swap)
  auto r = __builtin_amdgcn_permlane32_swap(a, b, false, false);
  a = (unsigned)r[0]; b = (unsigned)r[1];
#else
  asm("v_permlane32_swap_b32 %0, %1" : "+v"(a), "+v"(b));
#endif
}
__device__ __forceinline__ void plswap_f(float &a, float &b) {
  unsigned ua = __builtin_bit_cast(unsigned, a), ub = __builtin_bit_cast(unsigned, b);
  plswap_u(ua, ub);
  a = __builtin_bit_cast(float, ua); b = __builtin_bit_cast(float, ub);
}

__device__ __forceinline__ float tsum16(const f32x16 v) {
  float a = v[0] + v[8],  b = v[1] + v[9];
  float c = v[2] + v[10], d = v[3] + v[11];
  float e = v[4] + v[12], f = v[5] + v[13];
  float g = v[6] + v[14], h = v[7] + v[15];
  a += e; b += f; c += g; d += h;
  a += c; b += d;
  return a + b;
}

// ---------- fused prep: x cast (fp32->bf16) + all weight transposes ----------
__global__ __launch_bounds__(256) void prep_kernel(
    const float* __restrict__ x, const float* __restrict__ Wq,
    const float* __restrict__ Wk, const float* __restrict__ Wv,
    const float* __restrict__ Wproj, const float* __restrict__ W1,
    const float* __restrict__ W2, ushort4* __restrict__ xb4,
    u16* __restrict__ wqkv_t, u16* __restrict__ wproj_t,
    u16* __restrict__ w1_t, u16* __restrict__ w2_t) {
  const int i = blockIdx.x;
  if (i >= 3072) {
    int idx = (i - 3072) * 256 + threadIdx.x;
    float4 v = ((const float4*)x)[idx];
    ushort4 o; o.x = f2bf(v.x); o.y = f2bf(v.y); o.z = f2bf(v.z); o.w = f2bf(v.w);
    xb4[idx] = o;
    return;
  }
  const float* in; u16* out; int C, ldo, bx, by;
  if (i < 768) {
    int which = i >> 8, r = i & 255;
    const float* W = which == 0 ? Wq : (which == 1 ? Wk : Wv);
    int bz = r >> 5;
    in = W + bz * 32768;
    out = wqkv_t + which * 262144 + bz * 32768;
    C = 64; ldo = 512; bx = r & 1; by = (r >> 1) & 15;
  } else if (i < 1024) {
    int r = i - 768;
    in = Wproj; out = wproj_t; C = 512; ldo = 512; bx = r & 15; by = r >> 4;
  } else if (i < 2048) {
    int r = i - 1024;
    in = W1; out = w1_t; C = 2048; ldo = 512; bx = r & 63; by = r >> 6;
  } else {
    int r = i - 2048;
    in = W2; out = w2_t; C = 512; ldo = 2048; bx = r & 15; by = r >> 4;
  }
  __shared__ float t[32][33];
  int c0 = bx * 32, r0 = by * 32;
  int tx = threadIdx.x & 31, ty = threadIdx.x >> 5;
#pragma unroll
  for (int k = 0; k < 4; k++)
    t[ty + 8 * k][tx] = in[(long)(r0 + ty + 8 * k) * C + c0 + tx];
  __syncthreads();
#pragma unroll
  for (int k = 0; k < 4; k++)
    out[(long)(c0 + ty + 8 * k) * ldo + r0 + tx] = f2bf(t[tx][ty + 8 * k]);
}

// ---------- GEMM: C[M,N] = A[M,K] @ Bt[N,K]^T, 128xBN tile, BK=64 ----------
// MODE 0: bf16. MODE 1: bf16 = acc+bias+bf2f(resb) (proj + residual xb).
// MODE 2: bf16 = relu(acc+bias). MODE 3: f32 = acc+bias+bf2f(resb).
// MODE 4: qkv — Q cols (<512) scaled by 0.125/ln2; K cols plain;
//         V cols (>=1024) written TRANSPOSED into vtOut[bh][e][t] (ushort4).
template <int MODE, int BN>
__global__ __launch_bounds__(256) void gemm_bt_kernel(
    const u16* __restrict__ A, const u16* __restrict__ Bt, void* __restrict__ Out,
    const float* __restrict__ bias, const u16* __restrict__ resb,
    u16* __restrict__ vtOut, int N, int K) {
  __shared__ __align__(16) char As[128 * 128];
  __shared__ __align__(16) char Bs[BN * 128];
  const int tid = threadIdx.x;
  const int lane = tid & 63, w = tid >> 6;
  const int l15 = lane & 15, l4 = lane >> 4;
  const int nx = gridDim.x, nwg = nx * gridDim.y;
  int id = blockIdx.y * nx + blockIdx.x;
  id = (id & 7) * (nwg >> 3) + (id >> 3);  // XCD-bijective (nwg % 8 == 0)
  const long m0 = (long)(id / nx) * 128;
  const long n0 = (long)(id % nx) * BN;
  const int wm = (w >> 1) * 64, wn = (w & 1) * (BN / 2);
  const int NB = BN / 32;

  f32x4 acc[4][NB] = {};

  for (int kt = 0; kt < K; kt += 64) {
#pragma unroll
    for (int i = 0; i < 4; i++) {
      int basechunk = i * 256 + w * 64;
      int chunk = basechunk + lane;
      int row = chunk >> 3, c = chunk & 7;
      int sc = c ^ (row & 7);
      gload16(A + (m0 + row) * K + kt + sc * 8, As + basechunk * 16);
    }
#pragma unroll
    for (int i = 0; i < BN / 32; i++) {
      int basechunk = i * 256 + w * 64;
      int chunk = basechunk + lane;
      int row = chunk >> 3, c = chunk & 7;
      int sc = c ^ (row & 7);
      gload16(Bt + (n0 + row) * K + kt + sc * 8, Bs + basechunk * 16);
    }
    __syncthreads();
#pragma unroll
    for (int kk = 0; kk < 2; kk++) {
      bf16x8 a[4], b[NB];
#pragma unroll
      for (int m = 0; m < 4; m++) {
        int row = wm + m * 16 + l15;
        int ch = (kk * 4 + l4) ^ (row & 7);
        a[m] = *(const bf16x8*)(As + row * 128 + ch * 16);
      }
#pragma unroll
      for (int n = 0; n < NB; n++) {
        int row = wn + n * 16 + l15;
        int ch = (kk * 4 + l4) ^ (row & 7);
        b[n] = *(const bf16x8*)(Bs + row * 128 + ch * 16);
      }
#pragma unroll
      for (int m = 0; m < 4; m++)
#pragma unroll
        for (int n = 0; n < NB; n++)
          acc[m][n] = __builtin_amdgcn_mfma_f32_16x16x32_bf16(a[m], b[n], acc[m][n], 0, 0, 0);
    }
    __syncthreads();
  }

#pragma unroll
  for (int m = 0; m < 4; m++) {
#pragma unroll
    for (int n = 0; n < NB; n++) {
      long gcol = n0 + wn + n * 16 + l15;
      if (MODE == 4) {
        long grow0 = m0 + wm + m * 16 + l4 * 4;
        if (gcol < 1024) {
          const float s = (gcol < 512) ? 0.18033688f : 1.0f;
#pragma unroll
          for (int r = 0; r < 4; r++)
            ((u16*)Out)[(grow0 + r) * N + gcol] = f2bf(acc[m][n][r] * s);
        } else {
          int bb = (int)(grow0 >> 12);
          long trow0 = grow0 & 4095;
          int hc = (int)(gcol - 1024);
          int bhh = bb * 8 + (hc >> 6), e = hc & 63;
          ushort4 o;
          o.x = f2bf(acc[m][n][0]);
          o.y = f2bf(acc[m][n][1]);
          o.z = f2bf(acc[m][n][2]);
          o.w = f2bf(acc[m][n][3]);
          *(ushort4*)(vtOut + (long)bhh * 262144 + (long)e * 4096 + trow0) = o;
        }
      } else {
#pragma unroll
        for (int r = 0; r < 4; r++) {
          long grow = m0 + wm + m * 16 + l4 * 4 + r;
          float v = acc[m][n][r];
          if (MODE == 0) {
            ((u16*)Out)[grow * N + gcol] = f2bf(v);
          } else if (MODE == 1) {
            v += bias[gcol] + bf2f(resb[grow * N + gcol]);
            ((u16*)Out)[grow * N + gcol] = f2bf(v);
          } else if (MODE == 2) {
            v += bias[gcol];
            v = v > 0.f ? v : 0.f;
            ((u16*)Out)[grow * N + gcol] = f2bf(v);
          } else {
            v += bias[gcol] + bf2f(resb[grow * N + gcol]);
            ((float*)Out)[grow * N + gcol] = v;
          }
        }
      }
    }
  }
}

// ---------- flash attention (causal), 256-row Q tiles, quarter-KV split ----------
// Q pre-scaled -> p = exp2(s) directly. 512 blocks, 2 chained items:
// block g runs item g then item 1023-g; steps (qt+1)+(16-qt) = 17 for EVERY
// block (per-slot sequential balance -> constant residency, no tail).
__global__ __launch_bounds__(512, 4) void attn_kernel(
    const u16* __restrict__ qkv, const u16* __restrict__ vt,
    u16* __restrict__ pacc, float* __restrict__ pli) {
  __shared__ __align__(16) char Ks[2][64 * 128];  // [buf][key][e] bf16
  __shared__ __align__(16) char Vs[2][64 * 128];  // [buf][e][key] bf16
  const int tid = threadIdx.x;
  const int lane = tid & 63, w = tid >> 6;   // w in 0..7
  const int l31 = lane & 31, l5 = lane >> 5;

  const int g = blockIdx.x;

  for (int it = 0; it < 2; ++it) {
    const int item = it ? 1023 - g : g;
    const int qt = item >> 6;          // 0..15
    const int bh = (item >> 2) & 15;
    const int qq = item & 3;           // KV quarter
    const int b = bh >> 3, h = bh & 7;
    const int qt0 = qt * 256;
    const int L = qt + 1;
    const int j0 = qq * L, j1 = j0 + L;
    const int jdiag = 4 * qt;
    const u16* qbase = qkv + (long)b * 4096 * 1536 + h * 64;
    const u16* kbase = qbase + 512;
    const u16* vtbase = vt + (long)bh * 64 * 4096;

    // Q direct to registers (B-operand layout): aq[kk] = Q[q=qrow][e=16kk+8*l5+j]
    const int qrow_g = qt0 + w * 32 + l31;
    bf16x8 aq[4];
    {
      const u16* qp = qbase + (long)qrow_g * 1536 + l5 * 8;
#pragma unroll
      for (int kk = 0; kk < 4; kk++) aq[kk] = *(const bf16x8*)(qp + kk * 16);
    }

    // staging pointers (incremented per step)
    const int srow = tid >> 3, sc = (tid & 7) ^ (srow & 7);
    const u16* kp = kbase + (long)(j0 * 64 + srow) * 1536 + sc * 8;
    const u16* vp = vtbase + (long)srow * 4096 + j0 * 64 + sc * 8;
    gload16(kp, Ks[0] + w * 1024);
    gload16(vp, Vs[0] + w * 1024);
    __syncthreads();

    f32x16 oacc[2] = {};
    float li = 0.f;

    for (int j = j0; j < j1; ++j) {
      const int cur = (j - j0) & 1;
      if (j + 1 < j1) {
        kp += 64 * 1536;
        vp += 64;
        gload16(kp, Ks[cur ^ 1] + w * 1024);
        gload16(vp, Vs[cur ^ 1] + w * 1024);
      }

      const bool diag = (j >= jdiag);
      const int thr = qrow_g - j * 64;  // key_local <= thr is valid

      // two independent 32-key halves; st lives briefly -> arch VGPRs
#pragma unroll
      for (int n = 0; n < 2; n++) {
        // S^T[key][q] = K @ Q^T : key = n*32 + 4*l5 + (reg&3) + 8*(reg>>2), q = l31
        f32x16 st = {};
        __builtin_amdgcn_s_setprio(1);
#pragma unroll
        for (int kk = 0; kk < 4; kk++) {
          int ch = ((l5 + 2 * kk) ^ (l31 & 7)) * 16;
          bf16x8 ak = *(const bf16x8*)(Ks[cur] + (n * 32 + l31) * 128 + ch);
          st = __builtin_amdgcn_mfma_f32_32x32x16_bf16(ak, aq[kk], st, 0, 0, 0);
        }
        __builtin_amdgcn_s_setprio(0);

        if (diag) {
#pragma unroll
          for (int reg = 0; reg < 16; reg++) {
            int key = n * 32 + 4 * l5 + (reg & 3) + 8 * (reg >> 2);
            if (key > thr) st[reg] = -1e30f;
          }
        }

        // scale-free exp: p = exp2(s); masked -> 0
#pragma unroll
        for (int reg = 0; reg < 16; reg++)
          st[reg] = exp2f(st[reg]);
        li += tsum16(st);

        // pack to bf16, exchange halves, and immediately PV this 32-key half
#pragma unroll
        for (int jj = 0; jj < 2; jj++) {
          unsigned w0, w1, w2, w3;
          {
            unsigned pa, pb;
            asm("v_cvt_pk_bf16_f32 %0, %1, %2" : "=v"(pa) : "v"(st[(2 * jj) * 4 + 0]), "v"(st[(2 * jj) * 4 + 1]));
            asm("v_cvt_pk_bf16_f32 %0, %1, %2" : "=v"(pb) : "v"(st[(2 * jj + 1) * 4 + 0]), "v"(st[(2 * jj + 1) * 4 + 1]));
            plswap_u(pa, pb);
            w0 = pa; w2 = pb;
          }
          {
            unsigned pa, pb;
            asm("v_cvt_pk_bf16_f32 %0, %1, %2" : "=v"(pa) : "v"(st[(2 * jj) * 4 + 2]), "v"(st[(2 * jj) * 4 + 3]));
            asm("v_cvt_pk_bf16_f32 %0, %1, %2" : "=v"(pb) : "v"(st[(2 * jj + 1) * 4 + 2]), "v"(st[(2 * jj + 1) * 4 + 3]));
            plswap_u(pa, pb);
            w1 = pa; w3 = pb;
          }
          union { unsigned u[4]; bf16x8 v; } bp;
          bp.u[0] = w0; bp.u[1] = w1; bp.u[2] = w2; bp.u[3] = w3;
          int s2 = 2 * n + jj;
          int ch = ((l5 + 2 * s2) ^ (l31 & 7)) * 16;
          bf16x8 av0 = *(const bf16x8*)(Vs[cur] + l31 * 128 + ch);
          bf16x8 av1 = *(const bf16x8*)(Vs[cur] + (32 + l31) * 128 + ch);
          __builtin_amdgcn_s_setprio(1);
          oacc[0] = __builtin_amdgcn_mfma_f32_32x32x16_bf16(av0, bp.v, oacc[0], 0, 0, 0);
          oacc[1] = __builtin_amdgcn_mfma_f32_32x32x16_bf16(av1, bp.v, oacc[1], 0, 0, 0);
          __builtin_amdgcn_s_setprio(0);
        }
      }
      __syncthreads();  // drains prefetch; fences Ks/Vs buffer reuse
    }

    // cross-half li reduce (once per item)
    {
      float ta = li, tb = li;
      plswap_f(ta, tb);
      li = ta + tb;
    }

    // write partial: pacc bf16 [item][256 q][64 e] (unnormalized), pli[item][256 q]
    u16* pa = pacc + (long)item * 16384;
#pragma unroll
    for (int ne = 0; ne < 2; ne++)
#pragma unroll
      for (int gg = 0; gg < 4; gg++) {
        ushort4 o;
        o.x = f2bf(oacc[ne][4 * gg + 0]);
        o.y = f2bf(oacc[ne][4 * gg + 1]);
        o.z = f2bf(oacc[ne][4 * gg + 2]);
        o.w = f2bf(oacc[ne][4 * gg + 3]);
        *(ushort4*)(pa + (w * 32 + l31) * 64 + ne * 32 + 4 * l5 + 8 * gg) = o;
      }
    if (l5 == 0) pli[(long)item * 256 + w * 32 + l31] = li;
  }
}

// ---------- merge the four KV quarters: O = sum(acc_q) / sum(li_q) ----------
// 1024 blocks (4/CU): block = tile*4 + rowgroup; each handles 64 of 256 rows.
__global__ __launch_bounds__(256) void attn_merge_kernel(
    const u16* __restrict__ pacc, const float* __restrict__ pli, u16* __restrict__ attnb) {
  int tile = blockIdx.x >> 2;      // qt*16 + bh
  int rg = blockIdx.x & 3;         // row group (64 rows)
  int qt = tile >> 4, bh = tile & 15;
  int b = bh >> 3, h = bh & 7;
  int ibase = qt * 64 + bh * 4;
  const u16* pq[4];
  const float* lq[4];
#pragma unroll
  for (int q = 0; q < 4; q++) {
    pq[q] = pacc + (long)(ibase + q) * 16384;
    lq[q] = pli + (long)(ibase + q) * 256;
  }
  int t = threadIdx.x;
  int cg = (t & 15) * 4;
  int rsub = t >> 4;
#pragma unroll
  for (int pass = 0; pass < 4; ++pass) {
    int row = rg * 64 + pass * 16 + rsub;
    float denom = lq[0][row] + lq[1][row] + lq[2][row] + lq[3][row];
    float acc0 = 0.f, acc1 = 0.f, acc2 = 0.f, acc3 = 0.f;
#pragma unroll
    for (int q = 0; q < 4; q++) {
      ushort4 u = *(const ushort4*)(pq[q] + row * 64 + cg);
      acc0 += bf2f(u.x);
      acc1 += bf2f(u.y);
      acc2 += bf2f(u.z);
      acc3 += bf2f(u.w);
    }
    float inv = 1.f / denom;
    ushort4 o;
    o.x = f2bf(acc0 * inv);
    o.y = f2bf(acc1 * inv);
    o.z = f2bf(acc2 * inv);
    o.w = f2bf(acc3 * inv);
    *(ushort4*)(attnb + ((long)(b * 4096 + qt * 256 + row)) * 512 + h * 64 + cg) = o;
  }
}

extern "C" void kernel_launch(void* const* d_in, const int* in_sizes, int n_in,
                              void* d_out, int out_size, void* d_ws, size_t ws_size,
                              hipStream_t stream) {
  const float* x = (const float*)d_in[0];
  const float* Wq = (const float*)d_in[1];
  const float* Wk = (const float*)d_in[2];
  const float* Wv = (const float*)d_in[3];
  const float* Wproj = (const float*)d_in[4];
  const float* bproj = (const float*)d_in[5];
  const float* W1 = (const float*)d_in[6];
  const float* b1 = (const float*)d_in[7];
  const float* W2 = (const float*)d_in[8];
  const float* b2 = (const float*)d_in[9];

  char* ws = (char*)d_ws;
  u16* xb      = (u16*)(ws);             // [8192][512]   bf16 x
  u16* wqkv_t  = (u16*)(ws + 8388608);   // [1536][512]
  u16* wproj_t = (u16*)(ws + 9961472);   // [512][512]
  u16* w1_t    = (u16*)(ws + 10485760);  // [2048][512]
  u16* w2_t    = (u16*)(ws + 12582912);  // [512][2048]
  u16* qkv     = (u16*)(ws + 14680064);  // [8192][1536]  (q pre-scaled; V cols unused)
  u16* vt      = (u16*)(ws + 39845888);  // [16][64][4096]
  u16* attnb   = (u16*)(ws + 48234496);  // [8192][512]
  u16* x1b     = (u16*)(ws + 56623104);  // [8192][512]   x + sa_out
  u16* hbuf    = (u16*)(ws + 65011712);  // [8192][2048]  relu(ffn1)
  // attention partials alias later-written buffers (safe by stream order):
  float* pli   = (float*)(ws + 56623104 + 2097152);  // 1MB inside x1b region
  u16* pacc    = (u16*)(ws + 65011712);              // 32MB inside hbuf region

  prep_kernel<<<7168, 256, 0, stream>>>(x, Wq, Wk, Wv, Wproj, W1, W2,
                                        (ushort4*)xb, wqkv_t, wproj_t, w1_t, w2_t);

  gemm_bt_kernel<4, 128><<<dim3(12, 64), 256, 0, stream>>>(xb, wqkv_t, qkv, nullptr, nullptr, vt, 1536, 512);
  attn_kernel<<<512, 512, 0, stream>>>(qkv, vt, pacc, pli);
  attn_merge_kernel<<<1024, 256, 0, stream>>>(pacc, pli, attnb);
  gemm_bt_kernel<1, 64><<<dim3(8, 64), 256, 0, stream>>>(attnb, wproj_t, x1b, bproj, xb, nullptr, 512, 512);
  gemm_bt_kernel<2, 128><<<dim3(16, 64), 256, 0, stream>>>(x1b, w1_t, hbuf, b1, nullptr, nullptr, 2048, 512);
  gemm_bt_kernel<3, 64><<<dim3(8, 64), 256, 0, stream>>>(hbuf, w2_t, d_out, b2, x1b, nullptr, 512, 2048);
}